// Round 16
// baseline (191.735 us; speedup 1.0000x reference)
//
#include <hip/hip_runtime.h>
#include <hip/hip_bf16.h>
#include <stdint.h>

// B=4, S=8192, E=1024, heads=16 -> math collapses to:
//   Q = x @ W1[0:1024].T ; A = per-64-col-block softmax(Q/4) ; out = A @ W2.T
static constexpr int MTOT = 32768;
static constexpr int KD   = 1024;
static constexpr int ND   = 1024;

static constexpr int BM = 256, BN = 256, BK = 64;
static constexpr int NT = KD / BK;              // 16 K-tiles (even)
static constexpr int BUF_BYTES = 65536;         // per-buffer: A 32K + B 32K
static constexpr int BOFF = 32768;              // B offset within buffer
static constexpr int HALF = 16384;              // one unit (128 rows x 64 cols bf16)

typedef __bf16 bf16x8 __attribute__((ext_vector_type(8)));
typedef float  f32x4  __attribute__((ext_vector_type(4)));

__device__ __forceinline__ unsigned short f2bf_rne(float f) {
  union { float f; uint32_t u; } c; c.f = f;
  uint32_t u = c.u;
  return (unsigned short)((u + 0x7fffu + ((u >> 16) & 1u)) >> 16);
}

// One kernel for all three casts (x, W1q, W2).
__global__ void cast_all(const float* __restrict__ x,
                         const float* __restrict__ W1,
                         const float* __restrict__ W2,
                         unsigned short* __restrict__ xb,
                         unsigned short* __restrict__ w1b,
                         unsigned short* __restrict__ w2b) {
  constexpr int n4x = MTOT * KD / 4;
  constexpr int n4w = KD * KD / 4;
  constexpr int total = n4x + 2 * n4w;
  int idx = blockIdx.x * blockDim.x + threadIdx.x;
  int stride = gridDim.x * blockDim.x;
  for (int i = idx; i < total; i += stride) {
    const float* s; unsigned short* d; int j;
    if (i < n4x)            { s = x;  d = xb;  j = i; }
    else if (i < n4x + n4w) { s = W1; d = w1b; j = i - n4x; }
    else                    { s = W2; d = w2b; j = i - n4x - n4w; }
    float4 v = reinterpret_cast<const float4*>(s)[j];
    ushort4 o;
    o.x = f2bf_rne(v.x); o.y = f2bf_rne(v.y);
    o.z = f2bf_rne(v.z); o.w = f2bf_rne(v.w);
    reinterpret_cast<ushort4*>(d)[j] = o;
  }
}

__device__ __forceinline__ void gload_lds16(const void* g, void* lds) {
  __builtin_amdgcn_global_load_lds(
      (const __attribute__((address_space(1))) unsigned int*)g,
      (__attribute__((address_space(3))) unsigned int*)lds, 16, 0, 0);
}

// r16: fully software-pipelined LDS reads. Every MFMA cluster consumes
// fragments read >=1 phase earlier; NO manual lgkmcnt (compiler emits precise
// counted waits that are non-blocking at this distance). Quadrant order
// (a0,b01)(a1,b01)(a1,b23)(a0,b23) so each frag's registers are dead exactly
// when refilled. 4 barriers/tile {P1-end, P2-end, P3-int(post-vmcnt), P4-end};
// counted vmcnt(4) (never 0). Keeps T1 XCD swizzle, T2 LDS swizzle, setprio,
// r15 epilogues.
template <int SOFTMAX>
__global__ __launch_bounds__(512, 2)
void gemm8(const unsigned short* __restrict__ A,
           const unsigned short* __restrict__ Bm,
           void* __restrict__ Cout) {
  extern __shared__ __align__(16) char ldsc[];

  const int tid  = threadIdx.x;
  const int lane = tid & 63;
  const int wid  = tid >> 6;
  const int wm = wid >> 2, wn = wid & 3;       // wave tile: 128 rows x 64 cols
  const int fr = lane & 15, fq = lane >> 4;

  // T1: bijective XCD swizzle (512 blocks, 8 XCDs, 64 blocks/chunk).
  const int bid0 = blockIdx.x;
  const int bid  = ((bid0 & 7) << 6) | (bid0 >> 3);
  const int brow = (bid >> 2) * BM;
  const int bcol = (bid & 3) * BN;

  // staging: linear LDS dest + inverse-swizzled global src (rule #21).
  const int srow  = tid >> 3;                              // 0..63
  const int sslot = (tid & 7) ^ (srow & 7);
  const unsigned short* gA = A  + (size_t)(brow + srow) * KD + sslot * 8;
  const unsigned short* gB = Bm + (size_t)(bcol + srow) * KD + sslot * 8;

  f32x4  acc[8][4] = {};
  bf16x8 a0[4][2], a1[4][2], b01[2][2], b23[2][2];

  auto STAGE = [&](const unsigned short* g, int h, int kt, int b, int opOff) {
    const unsigned short* gu = g + (size_t)(h * 128) * KD + kt * BK;
    char* du = ldsc + b * BUF_BYTES + opOff + h * HALF + (wid << 10);
    gload_lds16(gu, du);
    gload_lds16(gu + (size_t)64 * KD, du + 8192);
  };

  auto rdA = [&](int b, bf16x8 (*dst)[2], int mBase) {
    const char* base = ldsc + b * BUF_BYTES + wm * HALF;
    #pragma unroll
    for (int mm = 0; mm < 4; ++mm) {
      const int r = (mBase + mm) * 16 + fr;
      #pragma unroll
      for (int ks = 0; ks < 2; ++ks)
        dst[mm][ks] = *(const bf16x8*)(base + (r << 7) +
                        ((ks * 64 + fq * 16) ^ ((r & 7) << 4)));
    }
  };
  auto rdB = [&](int b, int nBase, bf16x8 (*dst)[2]) {
    const char* base = ldsc + b * BUF_BYTES + BOFF + (wn >> 1) * HALF;
    #pragma unroll
    for (int nn = 0; nn < 2; ++nn) {
      const int r = (wn & 1) * 64 + (nBase + nn) * 16 + fr;
      #pragma unroll
      for (int ks = 0; ks < 2; ++ks)
        dst[nn][ks] = *(const bf16x8*)(base + (r << 7) +
                       ((ks * 64 + fq * 16) ^ ((r & 7) << 4)));
    }
  };
  auto MFMA16 = [&](int mBase, int nBase, bf16x8 (*af)[2], bf16x8 (*bf)[2]) {
    __builtin_amdgcn_s_setprio(1);
    #pragma unroll
    for (int ks = 0; ks < 2; ++ks)
      #pragma unroll
      for (int mm = 0; mm < 4; ++mm)
        #pragma unroll
        for (int nn = 0; nn < 2; ++nn)
          acc[mBase + mm][nBase + nn] = __builtin_amdgcn_mfma_f32_16x16x32_bf16(
              af[mm][ks], bf[nn][ks], acc[mBase + mm][nBase + nn], 0, 0, 0);
    __builtin_amdgcn_s_setprio(0);
  };

  // Pipelined K-tile step. On entry: a0,b01 hold tile T frags (read during
  // tile T-1); a1,b23 free. Hazard seals (reader-retire-before-barrier):
  //  - STAGE B0(T+1)->nxt @P1: old readers (b01(T-1), read T-2 P3) retired
  //    before Q1(T-1) MFMA, sealed P1-end(T-1).            [>=4 barriers]
  //  - STAGE B1(T+1)->nxt @P2: old readers (b23(T-1), read P2(T-1)) retired
  //    before Q3(T-1) MFMA, sealed P4-end(T-1).            [>=2 barriers]
  //  - STAGE A(T+2)->cur  @P3: a0(T) readers retired before Q1 (P1-end);
  //    a1(T) readers retired before Q2 (P2-end).           [>=1 barrier]
  //  - reads of nxt (b01',a0') come after vmcnt(4)+P3-int barrier (tile T+1
  //    visible to all waves).
  auto tileStep = [&](int T, int cur, int nxt) {
    const int tp1 = (T + 1 < NT) ? T + 1 : NT - 1;
    const int tp2 = (T + 2 < NT) ? T + 2 : NT - 1;

    // P1: read a1(T) | stage B0(T+1) | MFMA (a0,b01) -- operands 1+ phase old
    rdA(cur, a1, 4);
    STAGE(gB, 0, tp1, nxt, BOFF);
    MFMA16(0, 0, a0, b01);
    __builtin_amdgcn_s_barrier();            // P1-end

    // P2: read b23(T) | stage B1(T+1) | MFMA (a1,b01); b01 dead after
    rdB(cur, 2, b23);
    STAGE(gB, 1, tp1, nxt, BOFF);
    MFMA16(4, 0, a1, b01);
    __builtin_amdgcn_s_barrier();            // P2-end

    // P3: stage A(T+2)->cur, then per-tile counted vmcnt; read b01(T+1)
    STAGE(gA, 0, tp2, cur, 0);
    STAGE(gA, 1, tp2, cur, 0);
    // queue: [A(T+1)x4 (T-1 P3), B0(T+1)x2, B1(T+1)x2, A(T+2)x4] = 12
    asm volatile("s_waitcnt vmcnt(4)" ::: "memory"); // tile T+1 landed; A(T+2) flies
    __builtin_amdgcn_s_barrier();            // P3-int: T+1 visible to all
    rdB(nxt, 0, b01);                        // b01(T+1) -> used next-tile P1/P2
    MFMA16(4, 2, a1, b23);

    // P4: MFMA (a0,b23); refill a0 with tile T+1 (used next-tile P1)
    MFMA16(0, 2, a0, b23);
    rdA(nxt, a0, 0);
    __builtin_amdgcn_s_barrier();            // P4-end
  };

  // --- prologue: tile0 (4 units) + A of tile1; pre-read a0(0), b01(0) ---
  STAGE(gA, 0, 0, 0, 0);    STAGE(gA, 1, 0, 0, 0);
  STAGE(gB, 0, 0, 0, BOFF); STAGE(gB, 1, 0, 0, BOFF);
  STAGE(gA, 0, 1, 1, 0);    STAGE(gA, 1, 1, 1, 0);
  asm volatile("s_waitcnt vmcnt(4)" ::: "memory");   // tile0 landed; A(1) in flight
  __builtin_amdgcn_s_barrier();
  rdA(0, a0, 0);
  rdB(0, 0, b01);

  for (int T = 0; T < NT; T += 2) {
    tileStep(T,     0, 1);
    tileStep(T + 1, 1, 0);
  }

  if constexpr (SOFTMAX) {
    // logits = acc/4; softmax over the wave's 64-col block (= one head block)
    unsigned short* attn = reinterpret_cast<unsigned short*>(Cout);
    constexpr float CEXP = 0.25f * 1.44269504088896340736f; // log2(e)/4
    #pragma unroll
    for (int m = 0; m < 8; ++m) {
      const int row = brow + wm * 128 + m * 16 + fq * 4;
      #pragma unroll
      for (int j = 0; j < 4; ++j) {
        float v0 = acc[m][0][j], v1 = acc[m][1][j];
        float v2 = acc[m][2][j], v3 = acc[m][3][j];
        float mx = fmaxf(fmaxf(v0, v1), fmaxf(v2, v3));
        #pragma unroll
        for (int s = 1; s < 16; s <<= 1) mx = fmaxf(mx, __shfl_xor(mx, s, 64));
        float p0 = exp2f((v0 - mx) * CEXP);
        float p1 = exp2f((v1 - mx) * CEXP);
        float p2 = exp2f((v2 - mx) * CEXP);
        float p3 = exp2f((v3 - mx) * CEXP);
        float sm = p0 + p1 + p2 + p3;
        #pragma unroll
        for (int s = 1; s < 16; s <<= 1) sm += __shfl_xor(sm, s, 64);
        const float inv = 1.0f / sm;
        unsigned short* dst =
            attn + (size_t)(row + j) * ND + (bcol + wn * 64 + fr);
        dst[0]  = f2bf_rne(p0 * inv);
        dst[16] = f2bf_rne(p1 * inv);
        dst[32] = f2bf_rne(p2 * inv);
        dst[48] = f2bf_rne(p3 * inv);
      }
    }
  } else {
    // Vectorized f32 C-write via wave-private 16KB LDS bounce (r15).
    float* Cf = reinterpret_cast<float*>(Cout);
    char* wlds = ldsc + wid * 16384;
    #pragma unroll
    for (int h = 0; h < 2; ++h) {
      asm volatile("" ::: "memory");
      #pragma unroll
      for (int mm = 0; mm < 4; ++mm)
        #pragma unroll
        for (int n = 0; n < 4; ++n)
          #pragma unroll
          for (int j = 0; j < 4; ++j)
            *(float*)(wlds + (((mm * 16 + fq * 4 + j) << 6) + n * 16 + fr) * 4)
                = acc[4 * h + mm][n][j];
      asm volatile("s_waitcnt lgkmcnt(0)" ::: "memory"); // scatter visible
      const int rbase = brow + wm * 128 + h * 64;
      #pragma unroll
      for (int i = 0; i < 16; ++i) {
        const int idx16 = i * 64 + lane;     // 16B chunk id within 64x64 tile
        const int rl = idx16 >> 4;
        const int c4 = (idx16 & 15) << 2;
        f32x4 v = *(const f32x4*)(wlds + (size_t)idx16 * 16);
        *(f32x4*)(&Cf[(size_t)(rbase + rl) * ND + (bcol + wn * 64 + c4)]) = v;
      }
      asm volatile("s_waitcnt lgkmcnt(0)" ::: "memory"); // gather done pre-overwrite
    }
  }
}

extern "C" void kernel_launch(void* const* d_in, const int* in_sizes, int n_in,
                              void* d_out, int out_size, void* d_ws, size_t ws_size,
                              hipStream_t stream) {
  const float* x  = (const float*)d_in[0];   // [4,8192,1024] f32
  const float* W1 = (const float*)d_in[1];   // [3072,1024]  f32 (rows 0..1023 = Wq)
  const float* W2 = (const float*)d_in[2];   // [1024,1024]  f32
  float* out = (float*)d_out;

  char* ws = (char*)d_ws;
  unsigned short* xb   = (unsigned short*)(ws);
  unsigned short* w1b  = (unsigned short*)(ws + (size_t)67108864);
  unsigned short* w2b  = (unsigned short*)(ws + (size_t)69206016);
  unsigned short* attn = (unsigned short*)(ws + (size_t)71303168);

  hipFuncSetAttribute(reinterpret_cast<const void*>(gemm8<1>),
                      hipFuncAttributeMaxDynamicSharedMemorySize, 131072);
  hipFuncSetAttribute(reinterpret_cast<const void*>(gemm8<0>),
                      hipFuncAttributeMaxDynamicSharedMemorySize, 131072);

  cast_all<<<2048, 256, 0, stream>>>(x, W1, W2, xb, w1b, w2b);

  const int nblk = (MTOT / BM) * (ND / BN);   // 128 * 4 = 512
  gemm8<1><<<nblk, 512, 131072, stream>>>(xb, w1b, (void*)attn);
  gemm8<0><<<nblk, 512, 131072, stream>>>(attn, w2b, (void*)out);
}